// Round 11
// baseline (577.209 us; speedup 1.0000x reference)
//
#include <hip/hip_runtime.h>
#include <math.h>

#define BB 8
#define PP 64
#define LL 32
#define LMAXX 2048
#define INDIM 12
#define PNT 32
#define HIDD 128
#define TTCNN 127
#define NPATCH 512

#define EPI_NONE 0
#define EPI_RELU 1
#define EPI_GA   2
#define EPI_ADD  3

typedef __attribute__((ext_vector_type(8))) short short8v;
typedef __attribute__((ext_vector_type(4))) float float4v;

__device__ inline unsigned short f2bf(float f) {
    unsigned int u = __float_as_uint(f);
    unsigned int r = (u + 0x7FFFu + ((u >> 16) & 1u)) >> 16;
    return (unsigned short)r;
}

// ---------------------------------------------------------------- tables + W3 transpose (merged)
__global__ void tables_w3t_kernel(const float* __restrict__ W3, unsigned short* __restrict__ W3TB,
                                  float* __restrict__ tb, float* __restrict__ pe)
{
    int bid = blockIdx.x;
    if (bid < 2048) {
        int e = bid*256 + threadIdx.x;   // 4096*128 total
        int kk = e >> 12, cidx = e & 4095;
        float v = (kk < TTCNN && cidx < 4064) ? W3[kk*4064 + cidx] : 0.f;
        W3TB[cidx*128 + kk] = f2bf(v);
    } else {
        int e = (bid - 2048)*256 + threadIdx.x;
        if (e < 64*64) {
            int i = e >> 6, j = e & 63;
            float dist = fabsf((float)(i - j));   // DELTA/TAU = 1
            tb[e] = logf(expf(-dist) + 1e-12f);
        } else if (e < 64*64 + 64*128) {
            int e2 = e - 64*64;
            int i = e2 >> 7, d = e2 & 127;
            int mm = d >> 1;
            float div = expf((float)(2*mm) * (-logf(10000.f)/128.f));
            float ang = (float)i * div;
            pe[e2] = (d & 1) ? cosf(ang) : sinf(ang);
        }
    }
}

// ---------------------------------------------------------------- gather + time-encode + filter-gen MLP (fused)
__global__ void prep_h2_kernel(const float* __restrict__ data, const float* __restrict__ ts,
                               const float* __restrict__ pmask, const int* __restrict__ pindex,
                               const int* __restrict__ nbatch,
                               const float* __restrict__ teW, const float* __restrict__ teB,
                               const float* __restrict__ tePW, const float* __restrict__ tePB,
                               const float* __restrict__ W1, const float* __restrict__ b1,
                               const float* __restrict__ W2, const float* __restrict__ b2,
                               float* __restrict__ xint, float* __restrict__ maskout,
                               unsigned short* __restrict__ h2o)
{
    int n = blockIdx.x;
    int b = n >> 6, p = n & 63;
    __shared__ int s_start, s_len;
    __shared__ float s_mk[LL];
    __shared__ alignas(16) float Xs[LL*36];
    __shared__ alignas(16) float H1[LL*128];
    int tid = threadIdx.x;
    if (tid == 0) {
        int start = 0;
        for (int j = 0; j < p; ++j) {
            float mv = pmask[b*PP + j];
            int pi = pindex[b*PP + j];
            start += (mv > 0.f) ? (pi > 0 ? pi : 0) : 0;
        }
        float mvp = pmask[b*PP + p];
        int pip = pindex[b*PP + p];
        s_len = (mvp > 0.f) ? (pip > 0 ? pip : 0) : 0;
        s_start = start;
    }
    __syncthreads();
    int start = s_start, len = s_len, nb2 = nbatch[b];
    if (tid < LL) {
        int l = tid;
        int idx = start + l;
        float v = (l < len && idx < nb2) ? 1.f : 0.f;
        s_mk[l] = v;
        maskout[n*LL + l] = v;
    }
    __syncthreads();
    for (int e = tid; e < LL*PNT; e += 128) {
        int l = e >> 5, d = e & 31;
        float mv = s_mk[l];
        int idx = start + l;
        if (idx < 0) idx = 0;
        if (idx > LMAXX-1) idx = LMAXX-1;
        float val;
        if (d < INDIM) {
            val = (mv > 0.f) ? data[(b*LMAXX + idx)*INDIM + d] : 0.f;
        } else {
            float tsm = (mv > 0.f) ? ts[b*LMAXX + idx] : 0.f;
            if (d == INDIM) val = tsm * teW[0] + teB[0];
            else { int j = d - INDIM - 1; val = sinf(tsm * tePW[j] + tePB[j]); }
        }
        Xs[l*36 + d] = val;
        xint[n*(LL*PNT) + e] = val;
    }
    __syncthreads();
    int j = tid;  // 0..127
    float acc[LL];
    if (j < TTCNN) {
        #pragma unroll
        for (int l = 0; l < LL; ++l) acc[l] = b1[j];
        for (int d4 = 0; d4 < 8; ++d4) {
            float w0 = W1[(d4*4+0)*TTCNN + j];
            float w1 = W1[(d4*4+1)*TTCNN + j];
            float w2 = W1[(d4*4+2)*TTCNN + j];
            float w3 = W1[(d4*4+3)*TTCNN + j];
            #pragma unroll
            for (int l = 0; l < LL; ++l) {
                float4 x = *(float4*)&Xs[l*36 + d4*4];
                acc[l] = fmaf(x.x, w0, acc[l]);
                acc[l] = fmaf(x.y, w1, acc[l]);
                acc[l] = fmaf(x.z, w2, acc[l]);
                acc[l] = fmaf(x.w, w3, acc[l]);
            }
        }
        #pragma unroll
        for (int l = 0; l < LL; ++l) H1[l*128 + j] = fmaxf(acc[l], 0.f);
    } else {
        #pragma unroll
        for (int l = 0; l < LL; ++l) H1[l*128 + 127] = 0.f;
    }
    __syncthreads();
    if (j < TTCNN) {
        #pragma unroll
        for (int l = 0; l < LL; ++l) acc[l] = b2[j];
        for (int k4 = 0; k4 < 32; ++k4) {
            int k = k4*4;
            float w0 = W2[(k+0)*TTCNN + j];
            float w1 = W2[(k+1)*TTCNN + j];
            float w2 = W2[(k+2)*TTCNN + j];
            float w3 = (k+3 < TTCNN) ? W2[(k+3)*TTCNN + j] : 0.f;
            #pragma unroll
            for (int l = 0; l < LL; ++l) {
                float4 h = *(float4*)&H1[l*128 + k];
                acc[l] = fmaf(h.x, w0, acc[l]);
                acc[l] = fmaf(h.y, w1, acc[l]);
                acc[l] = fmaf(h.z, w2, acc[l]);
                acc[l] = fmaf(h.w, w3, acc[l]);
            }
        }
        #pragma unroll
        for (int l = 0; l < LL; ++l) h2o[(n*LL + l)*128 + j] = f2bf(fmaxf(acc[l], 0.f));
    } else {
        #pragma unroll
        for (int l = 0; l < LL; ++l) h2o[(n*LL + l)*128 + 127] = 0;
    }
}

// ---------------------------------------------------------------- MFMA Filt GEMM + softmax + TTCN contraction (unchanged)
__global__ __launch_bounds__(256) void ttcn_mfma_kernel(
    const unsigned short* __restrict__ h2b,
    const float* __restrict__ xint,
    const float* __restrict__ mask,
    const unsigned short* __restrict__ w3tb,
    const float* __restrict__ b3,
    const float* __restrict__ tbias,
    float* __restrict__ x)
{
    int bid = blockIdx.x;
    int n = bid >> 3, chunk = bid & 7;
    __shared__ alignas(16) unsigned short h2s[32*136];
    __shared__ alignas(16) float Xs[32*36];
    __shared__ float mk[32];
    int tid = threadIdx.x;
    for (int f = tid; f < 512; f += 256) {
        int l = f >> 4, c16 = f & 15;
        *(short8v*)&h2s[l*136 + c16*8] = *(const short8v*)&h2b[(n*32 + l)*128 + c16*8];
    }
    {
        int l = tid >> 3, d4 = (tid & 7)*4;
        *(float4*)&Xs[l*36 + d4] = *(const float4*)&xint[n*1024 + l*32 + d4];
    }
    if (tid < 32) mk[tid] = mask[n*32 + tid];
    __syncthreads();
    if (chunk == 0 && tid == 0) {
        float e = 0.f;
        for (int l = 0; l < 32; ++l) e += mk[l];
        x[n*HIDD + 127] = (e > 0.f) ? 1.f : 0.f;
    }
    int wave = tid >> 6, lane = tid & 63;
    int li = lane & 15, hi = lane >> 4;
    short8v a[2][4];
    #pragma unroll
    for (int mt = 0; mt < 2; ++mt)
        #pragma unroll
        for (int kk = 0; kk < 4; ++kk)
            a[mt][kk] = *(short8v*)&h2s[(mt*16 + li)*136 + kk*32 + hi*8];
    float mkr[8], off8[8], xv0[8], xv1[8];
    #pragma unroll
    for (int mt = 0; mt < 2; ++mt)
        #pragma unroll
        for (int r4 = 0; r4 < 4; ++r4) {
            int i = mt*4 + r4;
            int rr = mt*16 + hi*4 + r4;
            float mv = mk[rr];
            mkr[i] = mv;
            off8[i] = (1.f - mv) * (-30.f);
            xv0[i] = Xs[rr*36 + li];
            xv1[i] = Xs[rr*36 + 16 + li];
        }
    int cwbase = chunk*512 + wave*128;
    for (int tl = 0; tl < 4; ++tl) {
        int c0 = cwbase + tl*32;
        float4v acc[2][2] = {};
        #pragma unroll
        for (int nt2 = 0; nt2 < 2; ++nt2) {
            const unsigned short* bp = &w3tb[(size_t)(c0 + nt2*16 + li)*128 + hi*8];
            #pragma unroll
            for (int kk = 0; kk < 4; ++kk) {
                short8v bf = *(const short8v*)&bp[kk*32];
                acc[0][nt2] = __builtin_amdgcn_mfma_f32_16x16x32_bf16(a[0][kk], bf, acc[0][nt2], 0, 0, 0);
                acc[1][nt2] = __builtin_amdgcn_mfma_f32_16x16x32_bf16(a[1][kk], bf, acc[1][nt2], 0, 0, 0);
            }
        }
        int t = c0 >> 5;
        float colv2 = 0.f;
        #pragma unroll
        for (int nt2 = 0; nt2 < 2; ++nt2) {
            int cglob = c0 + nt2*16 + li;
            float bv = (cglob < 4064) ? b3[cglob] : 0.f;
            float s = 0.f, w = 0.f;
            #pragma unroll
            for (int mt = 0; mt < 2; ++mt)
                #pragma unroll
                for (int r4 = 0; r4 < 4; ++r4) {
                    int i = mt*4 + r4;
                    float fm = (acc[mt][nt2][r4] + bv)*mkr[i] + off8[i];
                    float e = __expf(fm);
                    s += e;
                    w = fmaf(e, (nt2 == 0) ? xv0[i] : xv1[i], w);
                }
            s += __shfl_xor(s, 16); w += __shfl_xor(w, 16);
            s += __shfl_xor(s, 32); w += __shfl_xor(w, 32);
            colv2 = fmaf(w, __builtin_amdgcn_rcpf(s), colv2);
        }
        colv2 += __shfl_xor(colv2, 1);
        colv2 += __shfl_xor(colv2, 2);
        colv2 += __shfl_xor(colv2, 4);
        colv2 += __shfl_xor(colv2, 8);
        if (lane == 0 && t < TTCNN)
            x[n*HIDD + t] = fmaxf(colv2 + tbias[t], 0.f);
    }
}

// ---------------------------------------------------------------- col-split linear (used for qkv0 only)
__global__ __launch_bounds__(256) void lin32_kernel(
    const float* __restrict__ A, int lda,
    const float* __restrict__ W0, const float* __restrict__ b0,
    const float* __restrict__ W1, const float* __restrict__ b1,
    const float* __restrict__ W2, const float* __restrict__ b2,
    float* __restrict__ O0, float* __restrict__ O1, float* __restrict__ O2,
    int K, int N, int epi,
    const float* __restrict__ xres, float* __restrict__ xlast_out,
    const float* __restrict__ pmk, const float* __restrict__ pe)
{
    __shared__ alignas(16) float As[8][132];
    int tid = threadIdx.x;
    int r = tid >> 5, c = tid & 31;
    int row = blockIdx.x*8 + r;
    int col = blockIdx.z*32 + c;
    const float* W; const float* Wb; float* O;
    if (blockIdx.y == 0)      { W = W0; Wb = b0; O = O0; }
    else if (blockIdx.y == 1) { W = W1; Wb = b1; O = O1; }
    else                      { W = W2; Wb = b2; O = O2; }
    float a0 = 0.f, a1 = 0.f, a2 = 0.f, a3 = 0.f;
    for (int kc = 0; kc < K; kc += 128) {
        __syncthreads();
        {
            int lr = tid >> 5, f4 = (tid & 31)*4;
            *(float4*)&As[lr][f4] = *(const float4*)&A[(size_t)(blockIdx.x*8 + lr)*lda + kc + f4];
        }
        __syncthreads();
        const float* wp = &W[(size_t)kc*N + col];
        #pragma unroll
        for (int k4 = 0; k4 < 32; ++k4) {
            float4 av = *(float4*)&As[r][k4*4];
            float w0_ = wp[(size_t)(k4*4+0)*N];
            float w1_ = wp[(size_t)(k4*4+1)*N];
            float w2_ = wp[(size_t)(k4*4+2)*N];
            float w3_ = wp[(size_t)(k4*4+3)*N];
            a0 = fmaf(av.x, w0_, a0);
            a1 = fmaf(av.y, w1_, a1);
            a2 = fmaf(av.z, w2_, a2);
            a3 = fmaf(av.w, w3_, a3);
        }
    }
    float val = (a0 + a1) + (a2 + a3) + Wb[col];
    if (epi == EPI_NONE) {
        O[(size_t)row*N + col] = val;
    } else if (epi == EPI_RELU) {
        O[(size_t)row*N + col] = fmaxf(val, 0.f);
    } else if (epi == EPI_GA) {
        float xr = xres[row*128 + col];
        float pmv = pmk[row];
        float pev = pe[(row & 63)*128 + col];
        xlast_out[row*128 + col] = xr;
        O[row*128 + col] = xr + val*pmv + pev;
    } else {
        O[row*128 + col] = xres[row*128 + col] + val;
    }
}

// ---------------------------------------------------------------- ga out-proj + GA epilogue + tf QKV (fused, 4 rows/block)
__global__ __launch_bounds__(256) void gaqkv_kernel(
    const float* __restrict__ ATT, const float* __restrict__ X,
    const float* __restrict__ pmk, const float* __restrict__ pe,
    const float* __restrict__ Wo, const float* __restrict__ bo,
    const float* __restrict__ Wq, const float* __restrict__ bq,
    const float* __restrict__ Wk, const float* __restrict__ bk,
    const float* __restrict__ Wv, const float* __restrict__ bv,
    float* __restrict__ Xout, float* __restrict__ XLASTo,
    float* __restrict__ Qo, float* __restrict__ Ko, float* __restrict__ Vo)
{
    __shared__ alignas(16) float att4[4][132];
    __shared__ alignas(16) float xf[4][132];
    int tid = threadIdx.x;
    int r0 = blockIdx.x*4;
    if (tid < 128) {
        int lr = tid >> 5, f4 = (tid & 31)*4;
        *(float4*)&att4[lr][f4] = *(const float4*)&ATT[(r0 + lr)*128 + f4];
    } else {
        int t = tid - 128;
        int lr = t >> 5, f4 = (t & 31)*4;
        *(float4*)&xf[lr][f4] = *(const float4*)&X[(r0 + lr)*128 + f4];
    }
    __syncthreads();
    int col = tid & 127, rp = tid >> 7;   // rows rp and rp+2
    float a0 = bo[col], a1 = bo[col];
    #pragma unroll 8
    for (int k = 0; k < 128; ++k) {
        float w = Wo[k*128 + col];
        a0 = fmaf(att4[rp][k], w, a0);
        a1 = fmaf(att4[rp+2][k], w, a1);
    }
    int gr0 = r0 + rp, gr1 = r0 + rp + 2;
    float x0 = xf[rp][col], x1 = xf[rp+2][col];
    XLASTo[gr0*128 + col] = x0;
    XLASTo[gr1*128 + col] = x1;
    float xn0 = x0 + a0*pmk[gr0] + pe[(gr0 & 63)*128 + col];
    float xn1 = x1 + a1*pmk[gr1] + pe[(gr1 & 63)*128 + col];
    Xout[gr0*128 + col] = xn0;
    Xout[gr1*128 + col] = xn1;
    xf[rp][col] = xn0;
    xf[rp+2][col] = xn1;
    __syncthreads();
    // tf qkv from xf
    float q0 = bq[col], q1 = bq[col];
    float k0 = bk[col], k1 = bk[col];
    float v0 = bv[col], v1 = bv[col];
    #pragma unroll 4
    for (int k = 0; k < 128; ++k) {
        float xa = xf[rp][k], xb = xf[rp+2][k];
        float wq = Wq[k*128 + col];
        float wk = Wk[k*128 + col];
        float wv = Wv[k*128 + col];
        q0 = fmaf(xa, wq, q0); q1 = fmaf(xb, wq, q1);
        k0 = fmaf(xa, wk, k0); k1 = fmaf(xb, wk, k1);
        v0 = fmaf(xa, wv, v0); v1 = fmaf(xb, wv, v1);
    }
    Qo[gr0*128 + col] = q0; Qo[gr1*128 + col] = q1;
    Ko[gr0*128 + col] = k0; Ko[gr1*128 + col] = k1;
    Vo[gr0*128 + col] = v0; Vo[gr1*128 + col] = v1;
}

// ---------------------------------------------------------------- mega FF: tf-out + LN1 + FF1 + FF2 + LN2 + residual + next QKV
__global__ __launch_bounds__(256) void megaff_kernel(
    const float* __restrict__ ATT, const float* __restrict__ X,
    const float* __restrict__ XLAST, const float* __restrict__ pmk,
    const float* __restrict__ Wo, const float* __restrict__ bo,
    const float* __restrict__ g1, const float* __restrict__ bt1,
    const float* __restrict__ W1, const float* __restrict__ b1,
    const float* __restrict__ W2, const float* __restrict__ b2,
    const float* __restrict__ g2, const float* __restrict__ bt2,
    const float* __restrict__ nWq, const float* __restrict__ nbq,
    const float* __restrict__ nWk, const float* __restrict__ nbk,
    const float* __restrict__ nWv, const float* __restrict__ nbv,
    float* __restrict__ Xout,
    float* __restrict__ Qo, float* __restrict__ Ko, float* __restrict__ Vo)
{
    __shared__ alignas(16) float att4[4][132];
    __shared__ alignas(16) float xn[4][132];
    __shared__ alignas(16) float tvb[4][132];
    __shared__ alignas(16) float xfb[4][132];
    __shared__ alignas(16) float h[4][2052];
    int tid = threadIdx.x;
    int r0 = blockIdx.x*4;
    // stage ATT (attn2 out) and X (post-ga x)
    if (tid < 128) {
        int lr = tid >> 5, f4 = (tid & 31)*4;
        *(float4*)&att4[lr][f4] = *(const float4*)&ATT[(r0 + lr)*128 + f4];
    } else {
        int t = tid - 128;
        int lr = t >> 5, f4 = (t & 31)*4;
        *(float4*)&xn[lr][f4] = *(const float4*)&X[(r0 + lr)*128 + f4];
    }
    __syncthreads();
    int col = tid & 127, rp = tid >> 7;   // rows rp, rp+2
    // tf out-proj, tv = x + a (in-place into xn, same-thread elements)
    {
        float a0 = bo[col], a1 = bo[col];
        #pragma unroll 8
        for (int k = 0; k < 128; ++k) {
            float w = Wo[k*128 + col];
            a0 = fmaf(att4[rp][k], w, a0);
            a1 = fmaf(att4[rp+2][k], w, a1);
        }
        xn[rp][col]   += a0;
        xn[rp+2][col] += a1;
    }
    __syncthreads();
    // LN1: wave per row (4 waves)
    {
        int row = tid >> 6, l = tid & 63;
        float v0 = xn[row][l], v1 = xn[row][l + 64];
        float s = v0 + v1, s2 = v0*v0 + v1*v1;
        for (int off = 32; off >= 1; off >>= 1) {
            s  += __shfl_xor(s,  off);
            s2 += __shfl_xor(s2, off);
        }
        float mean = s * (1.f/128.f);
        float var = s2 * (1.f/128.f) - mean*mean;
        float rs = rsqrtf(var + 1e-5f);
        xn[row][l]      = (v0 - mean)*rs*g1[l] + bt1[l];
        xn[row][l + 64] = (v1 - mean)*rs*g1[l + 64] + bt1[l + 64];
    }
    __syncthreads();
    // FF1: thread owns 8 adjacent cols x 4 rows
    {
        int c8 = tid*8;
        float acc[4][8];
        #pragma unroll
        for (int j = 0; j < 8; ++j) {
            float bj = b1[c8 + j];
            #pragma unroll
            for (int r = 0; r < 4; ++r) acc[r][j] = bj;
        }
        #pragma unroll 4
        for (int k = 0; k < 128; ++k) {
            float4 wA = *(const float4*)&W1[(size_t)k*2048 + c8];
            float4 wB = *(const float4*)&W1[(size_t)k*2048 + c8 + 4];
            float xk0 = xn[0][k], xk1 = xn[1][k], xk2 = xn[2][k], xk3 = xn[3][k];
            acc[0][0] = fmaf(xk0, wA.x, acc[0][0]); acc[0][1] = fmaf(xk0, wA.y, acc[0][1]);
            acc[0][2] = fmaf(xk0, wA.z, acc[0][2]); acc[0][3] = fmaf(xk0, wA.w, acc[0][3]);
            acc[0][4] = fmaf(xk0, wB.x, acc[0][4]); acc[0][5] = fmaf(xk0, wB.y, acc[0][5]);
            acc[0][6] = fmaf(xk0, wB.z, acc[0][6]); acc[0][7] = fmaf(xk0, wB.w, acc[0][7]);
            acc[1][0] = fmaf(xk1, wA.x, acc[1][0]); acc[1][1] = fmaf(xk1, wA.y, acc[1][1]);
            acc[1][2] = fmaf(xk1, wA.z, acc[1][2]); acc[1][3] = fmaf(xk1, wA.w, acc[1][3]);
            acc[1][4] = fmaf(xk1, wB.x, acc[1][4]); acc[1][5] = fmaf(xk1, wB.y, acc[1][5]);
            acc[1][6] = fmaf(xk1, wB.z, acc[1][6]); acc[1][7] = fmaf(xk1, wB.w, acc[1][7]);
            acc[2][0] = fmaf(xk2, wA.x, acc[2][0]); acc[2][1] = fmaf(xk2, wA.y, acc[2][1]);
            acc[2][2] = fmaf(xk2, wA.z, acc[2][2]); acc[2][3] = fmaf(xk2, wA.w, acc[2][3]);
            acc[2][4] = fmaf(xk2, wB.x, acc[2][4]); acc[2][5] = fmaf(xk2, wB.y, acc[2][5]);
            acc[2][6] = fmaf(xk2, wB.z, acc[2][6]); acc[2][7] = fmaf(xk2, wB.w, acc[2][7]);
            acc[3][0] = fmaf(xk3, wA.x, acc[3][0]); acc[3][1] = fmaf(xk3, wA.y, acc[3][1]);
            acc[3][2] = fmaf(xk3, wA.z, acc[3][2]); acc[3][3] = fmaf(xk3, wA.w, acc[3][3]);
            acc[3][4] = fmaf(xk3, wB.x, acc[3][4]); acc[3][5] = fmaf(xk3, wB.y, acc[3][5]);
            acc[3][6] = fmaf(xk3, wB.z, acc[3][6]); acc[3][7] = fmaf(xk3, wB.w, acc[3][7]);
        }
        #pragma unroll
        for (int r = 0; r < 4; ++r) {
            float4 o0 = make_float4(fmaxf(acc[r][0],0.f), fmaxf(acc[r][1],0.f),
                                    fmaxf(acc[r][2],0.f), fmaxf(acc[r][3],0.f));
            float4 o1 = make_float4(fmaxf(acc[r][4],0.f), fmaxf(acc[r][5],0.f),
                                    fmaxf(acc[r][6],0.f), fmaxf(acc[r][7],0.f));
            *(float4*)&h[r][c8]     = o0;
            *(float4*)&h[r][c8 + 4] = o1;
        }
    }
    __syncthreads();
    // FF2: thread (col, rows rp/rp+2), W2 column shared across rows, h broadcast reads
    {
        float f0 = b2[col], f1 = b2[col];
        #pragma unroll 8
        for (int k = 0; k < 2048; ++k) {
            float w = W2[(size_t)k*128 + col];
            f0 = fmaf(h[rp][k], w, f0);
            f1 = fmaf(h[rp+2][k], w, f1);
        }
        tvb[rp][col]   = xn[rp][col] + f0;
        tvb[rp+2][col] = xn[rp+2][col] + f1;
    }
    __syncthreads();
    // LN2 + final residual*pm, write Xout, keep xf for qkv
    {
        int row = tid >> 6, l = tid & 63;
        float v0 = tvb[row][l], v1 = tvb[row][l + 64];
        float s = v0 + v1, s2 = v0*v0 + v1*v1;
        for (int off = 32; off >= 1; off >>= 1) {
            s  += __shfl_xor(s,  off);
            s2 += __shfl_xor(s2, off);
        }
        float mean = s * (1.f/128.f);
        float var = s2 * (1.f/128.f) - mean*mean;
        float rs = rsqrtf(var + 1e-5f);
        float y0 = (v0 - mean)*rs*g2[l] + bt2[l];
        float y1 = (v1 - mean)*rs*g2[l + 64] + bt2[l + 64];
        int gr = r0 + row;
        float pmv = pmk[gr];
        float xf0 = (XLAST[gr*128 + l]      + y0)*pmv;
        float xf1 = (XLAST[gr*128 + l + 64] + y1)*pmv;
        Xout[gr*128 + l]      = xf0;
        Xout[gr*128 + l + 64] = xf1;
        xfb[row][l]      = xf0;
        xfb[row][l + 64] = xf1;
    }
    __syncthreads();
    // next-layer QKV (or cls K/V when nWq == nullptr)
    int gr0 = r0 + rp, gr1 = r0 + rp + 2;
    if (nWq) {
        float q0 = nbq[col], q1 = nbq[col];
        #pragma unroll 8
        for (int k = 0; k < 128; ++k) {
            float w = nWq[k*128 + col];
            q0 = fmaf(xfb[rp][k], w, q0);
            q1 = fmaf(xfb[rp+2][k], w, q1);
        }
        Qo[gr0*128 + col] = q0;
        Qo[gr1*128 + col] = q1;
    }
    {
        float k0 = nbk[col], k1 = nbk[col];
        #pragma unroll 8
        for (int k = 0; k < 128; ++k) {
            float w = nWk[k*128 + col];
            k0 = fmaf(xfb[rp][k], w, k0);
            k1 = fmaf(xfb[rp+2][k], w, k1);
        }
        Ko[gr0*128 + col] = k0;
        Ko[gr1*128 + col] = k1;
    }
    {
        float v0 = nbv[col], v1 = nbv[col];
        #pragma unroll 8
        for (int k = 0; k < 128; ++k) {
            float w = nWv[k*128 + col];
            v0 = fmaf(xfb[rp][k], w, v0);
            v1 = fmaf(xfb[rp+2][k], w, v1);
        }
        Vo[gr0*128 + col] = v0;
        Vo[gr1*128 + col] = v1;
    }
}

// ---------------------------------------------------------------- 64-token MHA (4 heads, dh=32), split q-rows x2 (unchanged)
__global__ __launch_bounds__(256) void attn_kernel(
    const float* __restrict__ q, const float* __restrict__ k, const float* __restrict__ v,
    float* __restrict__ out, const float* __restrict__ tb,
    const float* __restrict__ pmk, int flags)
{
    int bid = blockIdx.x;
    int b = bid >> 3, h = (bid >> 1) & 3, half = bid & 1;
    int rbase = half*32;
    __shared__ alignas(16) float qs[32*36];
    __shared__ alignas(16) float ks[64*36];
    __shared__ alignas(16) float vs[64*36];
    __shared__ float as_[32*68];
    int tid = threadIdx.x;
    {
        int m = tid >> 3, d4 = (tid & 7)*4;
        *(float4*)&qs[m*36 + d4] = *(const float4*)&q[(b*64 + rbase + m)*128 + h*32 + d4];
    }
    for (int f = tid; f < 512; f += 256) {
        int m = f >> 3, d4 = (f & 7)*4;
        int gofs = (b*64 + m)*128 + h*32 + d4;
        *(float4*)&ks[m*36 + d4] = *(const float4*)&k[gofs];
        *(float4*)&vs[m*36 + d4] = *(const float4*)&v[gofs];
    }
    __syncthreads();
    int r = tid >> 3, qd = tid & 7;
    float sreg[8];
    #pragma unroll
    for (int j = 0; j < 8; ++j) {
        int cc = j*8 + qd;
        float acc = 0.f;
        #pragma unroll
        for (int d4 = 0; d4 < 8; ++d4) {
            float4 a = *(float4*)&qs[r*36 + d4*4];
            float4 bb = *(float4*)&ks[cc*36 + d4*4];
            acc += a.x*bb.x + a.y*bb.y + a.z*bb.z + a.w*bb.w;
        }
        float s = acc * 0.17677669529663687f;
        if (flags & 1) s += tb[(rbase + r)*64 + cc];
        if (flags & 2) { if (pmk[b*64 + cc] <= 0.f) s = -1e9f; }
        sreg[j] = s;
    }
    float m = sreg[0];
    #pragma unroll
    for (int j = 1; j < 8; ++j) m = fmaxf(m, sreg[j]);
    m = fmaxf(m, __shfl_xor(m, 1));
    m = fmaxf(m, __shfl_xor(m, 2));
    m = fmaxf(m, __shfl_xor(m, 4));
    float ssum = 0.f;
    #pragma unroll
    for (int j = 0; j < 8; ++j) { sreg[j] = __expf(sreg[j] - m); ssum += sreg[j]; }
    ssum += __shfl_xor(ssum, 1);
    ssum += __shfl_xor(ssum, 2);
    ssum += __shfl_xor(ssum, 4);
    float inv = __builtin_amdgcn_rcpf(ssum);
    #pragma unroll
    for (int j = 0; j < 8; ++j) as_[r*68 + j*8 + qd] = sreg[j]*inv;
    __syncthreads();
    float o0 = 0.f, o1 = 0.f, o2 = 0.f, o3 = 0.f;
    int d0 = qd*4;
    for (int cc = 0; cc < 64; ++cc) {
        float a = as_[r*68 + cc];
        float4 v4 = *(float4*)&vs[cc*36 + d0];
        o0 += a*v4.x; o1 += a*v4.y; o2 += a*v4.z; o3 += a*v4.w;
    }
    *(float4*)&out[(b*64 + rbase + r)*128 + h*32 + d0] = make_float4(o0, o1, o2, o3);
}

// ---------------------------------------------------------------- cls: q-proj + attention + Weff logits (unchanged)
__global__ __launch_bounds__(256) void cls_attn_kernel(
    const float* __restrict__ clsq, const float* __restrict__ Wq, const float* __restrict__ bq,
    const float* __restrict__ k, const float* __restrict__ v,
    const float* __restrict__ pmk,
    const float* __restrict__ Wo, const float* __restrict__ bo,
    const float* __restrict__ WoutW, const float* __restrict__ boutB,
    float* __restrict__ outp)
{
    int b = blockIdx.x;
    __shared__ alignas(16) float ks[64*132];
    __shared__ alignas(16) float vs[64*132];
    __shared__ alignas(16) float q5[5*132];
    __shared__ float cq[5*128];
    __shared__ float sb[5*68];
    __shared__ float z[5*132];
    __shared__ float wef[129];
    int tid = threadIdx.x;
    for (int f = tid; f < 64*32; f += 256) {
        int m = f >> 5, d4 = (f & 31)*4;
        *(float4*)&ks[m*132 + d4] = *(const float4*)&k[(b*64+m)*128 + d4];
        *(float4*)&vs[m*132 + d4] = *(const float4*)&v[(b*64+m)*128 + d4];
    }
    for (int e = tid; e < 5*128; e += 256) {
        cq[e] = clsq[e];
        z[(e >> 7)*132 + (e & 127)] = 0.f;
    }
    __syncthreads();
    for (int it = tid; it < 5*128; it += 256) {
        int qr = it >> 7, d = it & 127;
        float a = bq[d];
        for (int kk = 0; kk < 128; ++kk) a += cq[qr*128 + kk]*Wq[kk*128 + d];
        q5[qr*132 + d] = a;
    }
    if (tid < 128) {
        float s = 0.f;
        for (int cc = 0; cc < 128; ++cc) s += Wo[tid*128 + cc]*WoutW[cc];
        wef[tid] = s;
    } else if (tid == 128) {
        float t = boutB[0];
        for (int cc = 0; cc < 128; ++cc) t += bo[cc]*WoutW[cc];
        wef[128] = t;
    }
    __syncthreads();
    for (int h = 0; h < 4; ++h) {
        for (int it = tid; it < 5*64; it += 256) {
            int qr = it >> 6, cc = it & 63;
            float acc = 0.f;
            #pragma unroll
            for (int d4 = 0; d4 < 8; ++d4) {
                float4 a = *(float4*)&q5[qr*132 + h*32 + d4*4];
                float4 bb = *(float4*)&ks[cc*132 + h*32 + d4*4];
                acc += a.x*bb.x + a.y*bb.y + a.z*bb.z + a.w*bb.w;
            }
            float s = acc * 0.17677669529663687f;
            if (pmk[b*64 + cc] <= 0.f) s = -1e9f;
            sb[qr*68 + cc] = s;
        }
        __syncthreads();
        if (tid < 5) {
            float m = -3e38f;
            for (int cc = 0; cc < 64; ++cc) m = fmaxf(m, sb[tid*68 + cc]);
            float ssum = 0.f;
            for (int cc = 0; cc < 64; ++cc) {
                float e = __expf(sb[tid*68 + cc] - m);
                sb[tid*68 + cc] = e;
                ssum += e;
            }
            float inv = __builtin_amdgcn_rcpf(ssum);
            for (int cc = 0; cc < 64; ++cc) sb[tid*68 + cc] *= inv;
        }
        __syncthreads();
        for (int it = tid; it < 5*32; it += 256) {
            int qr = it >> 5, d = it & 31;
            float acc = 0.f;
            for (int cc = 0; cc < 64; ++cc) acc += sb[qr*68 + cc]*vs[cc*132 + h*32 + d];
            z[qr*132 + h*32 + d] = acc;
        }
        __syncthreads();
    }
    if (tid < 5) {
        float acc = wef[128];
        for (int d = 0; d < 128; ++d) acc += z[tid*132 + d]*wef[d];
        outp[b*5 + tid] = acc;
    }
}

// ================================================================ launch
extern "C" void kernel_launch(void* const* d_in, const int* in_sizes, int n_in,
                              void* d_out, int out_size, void* d_ws, size_t ws_size,
                              hipStream_t stream)
{
    (void)n_in; (void)out_size; (void)ws_size;
    #define FP(i) ((const float*)d_in[i])
    const float* data = FP(0);
    const float* ts   = FP(1);
    const float* pmask= FP(2);
    const int*   pidx = (const int*)d_in[3];
    const int*   nb   = (const int*)d_in[4];
    const float* teW  = FP(5);
    const float* teB  = FP(6);
    const float* tePW = FP(7);
    const float* tePB = FP(8);
    const float* fgW1 = FP(9);
    const float* fgb1 = FP(10);
    const float* fgW2 = FP(11);
    const float* fgb2 = FP(12);
    const float* fgW3 = FP(13);
    const float* fgb3 = FP(14);
    const float* Tb   = FP(15);
    const float *gaWq,*gaWk,*gaWv,*gaWo,*tfWq,*tfWk,*tfWv,*tfWo;
    const float *gabq,*gabk,*gabv,*gabo,*tfbq,*tfbk,*tfbv,*tfbo,*ffb2;
    const float *ln1g,*ln1b,*ln2g,*ln2b,*ffW1,*ffb1,*ffW2;
    const float *clsq,*clsWq,*clsWk,*clsWv,*clsWo,*clsbq,*clsbk,*clsbv,*clsbo,*cloW,*clob;
    if (in_sizes[17] == 2*128*128) {  // setup_inputs dict order
        gaWq=FP(16); gaWk=FP(17); gaWv=FP(18); gaWo=FP(19);
        tfWq=FP(20); tfWk=FP(21); tfWv=FP(22); tfWo=FP(23);
        gabq=FP(24); gabk=FP(25); gabv=FP(26); gabo=FP(27);
        tfbq=FP(28); tfbk=FP(29); tfbv=FP(30); tfbo=FP(31);
        ffb2=FP(32); ln1g=FP(33); ln1b=FP(34); ln2g=FP(35); ln2b=FP(36);
        ffW1=FP(37); ffb1=FP(38); ffW2=FP(39);
        clsq=FP(40); clsWq=FP(41); clsWk=FP(42); clsWv=FP(43); clsWo=FP(44);
        clsbq=FP(45); clsbk=FP(46); clsbv=FP(47); clsbo=FP(48); cloW=FP(49); clob=FP(50);
    } else {                          // reference() signature order
        gaWq=FP(16); gabq=FP(17); gaWk=FP(18); gabk=FP(19);
        gaWv=FP(20); gabv=FP(21); gaWo=FP(22); gabo=FP(23);
        tfWq=FP(24); tfbq=FP(25); tfWk=FP(26); tfbk=FP(27);
        tfWv=FP(28); tfbv=FP(29); tfWo=FP(30); tfbo=FP(31);
        ln1g=FP(32); ln1b=FP(33); ffW1=FP(34); ffb1=FP(35); ffW2=FP(36); ffb2=FP(37);
        ln2g=FP(38); ln2b=FP(39);
        clsq=FP(40); clsWq=FP(41); clsbq=FP(42); clsWk=FP(43); clsbk=FP(44);
        clsWv=FP(45); clsbv=FP(46); clsWo=FP(47); clsbo=FP(48); cloW=FP(49); clob=FP(50);
    }

    float* ws   = (float*)d_ws;
    float* XINT = ws;
    float* MASK = ws + 524288;
    unsigned short* W3TB = (unsigned short*)(ws + 540672);
    unsigned short* H2Bb = (unsigned short*)(ws + 1060864);
    float* X    = ws + 3158016;
    float* XLAST= X + 65536;
    float* Q    = XLAST + 65536;
    float* Kb   = Q + 65536;
    float* Vb   = Kb + 65536;
    float* ATT  = Vb + 65536;
    float* TBT  = ATT + 65536;
    float* PET  = TBT + 4096;

    tables_w3t_kernel<<<2096, 256, 0, stream>>>(fgW3, W3TB, TBT, PET);
    prep_h2_kernel<<<512, 128, 0, stream>>>(data, ts, pmask, pidx, nb, teW, teB, tePW, tePB,
                                            fgW1, fgb1, fgW2, fgb2, XINT, MASK, H2Bb);
    ttcn_mfma_kernel<<<4096, 256, 0, stream>>>(H2Bb, XINT, MASK, W3TB, fgb3, Tb, X);

    // layer 0 ga qkv
    lin32_kernel<<<dim3(64,3,4), 256, 0, stream>>>(X, 128, gaWq,gabq, gaWk,gabk, gaWv,gabv, Q,Kb,Vb,
        128,128, EPI_NONE, nullptr,nullptr,nullptr,nullptr);

    for (int l = 0; l < 2; ++l) {
        const float* Wo  = gaWo + l*16384; const float* bo  = gabo + l*128;
        const float* Wq2 = tfWq + l*16384; const float* bq2 = tfbq + l*128;
        const float* Wk2 = tfWk + l*16384; const float* bk2 = tfbk + l*128;
        const float* Wv2 = tfWv + l*16384; const float* bv2 = tfbv + l*128;
        const float* Wo2 = tfWo + l*16384; const float* bo2 = tfbo + l*128;
        // ga attention
        attn_kernel<<<64, 256, 0, stream>>>(Q, Kb, Vb, ATT, TBT, pmask, 3);
        // ga out-proj + epilogue + tf qkv
        gaqkv_kernel<<<128, 256, 0, stream>>>(ATT, X, pmask, PET, Wo, bo,
                                              Wq2, bq2, Wk2, bk2, Wv2, bv2,
                                              X, XLAST, Q, Kb, Vb);
        // tf attention
        attn_kernel<<<64, 256, 0, stream>>>(Q, Kb, Vb, ATT, TBT, pmask, 0);
        // mega FF + next qkv (layer0 -> layer1 ga weights; layer1 -> cls k/v)
        if (l == 0) {
            megaff_kernel<<<128, 256, 0, stream>>>(ATT, X, XLAST, pmask,
                Wo2, bo2, ln1g, ln1b,
                ffW1, ffb1, ffW2, ffb2, ln2g, ln2b,
                gaWq + 16384, gabq + 128, gaWk + 16384, gabk + 128, gaWv + 16384, gabv + 128,
                X, Q, Kb, Vb);
        } else {
            megaff_kernel<<<128, 256, 0, stream>>>(ATT, X, XLAST, pmask,
                Wo2, bo2, ln1g + 128, ln1b + 128,
                ffW1 + (size_t)128*2048, ffb1 + 2048, ffW2 + (size_t)2048*128, ffb2 + 128,
                ln2g + 128, ln2b + 128,
                nullptr, nullptr, clsWk, clsbk, clsWv, clsbv,
                X, Q, Kb, Vb);
        }
    }

    cls_attn_kernel<<<8, 256, 0, stream>>>(clsq, clsWq, clsbq, Kb, Vb, pmask,
                                           clsWo, clsbo, cloW, clob, (float*)d_out);
}

// Round 12
// 422.461 us; speedup vs baseline: 1.3663x; 1.3663x over previous
//
#include <hip/hip_runtime.h>
#include <math.h>

#define BB 8
#define PP 64
#define LL 32
#define LMAXX 2048
#define INDIM 12
#define PNT 32
#define HIDD 128
#define TTCNN 127
#define NPATCH 512

#define EPI_NONE 0
#define EPI_RELU 1
#define EPI_GA   2
#define EPI_LN   3
#define EPI_LNF  4

typedef __attribute__((ext_vector_type(8))) short short8v;
typedef __attribute__((ext_vector_type(4))) float float4v;

__device__ inline unsigned short f2bf(float f) {
    unsigned int u = __float_as_uint(f);
    unsigned int r = (u + 0x7FFFu + ((u >> 16) & 1u)) >> 16;
    return (unsigned short)r;
}

// ---------------------------------------------------------------- tables + W3 transpose (merged)
__global__ void tables_w3t_kernel(const float* __restrict__ W3, unsigned short* __restrict__ W3TB,
                                  float* __restrict__ tb, float* __restrict__ pe)
{
    int bid = blockIdx.x;
    if (bid < 2048) {
        int e = bid*256 + threadIdx.x;   // 4096*128 total
        int kk = e >> 12, cidx = e & 4095;
        float v = (kk < TTCNN && cidx < 4064) ? W3[kk*4064 + cidx] : 0.f;
        W3TB[cidx*128 + kk] = f2bf(v);
    } else {
        int e = (bid - 2048)*256 + threadIdx.x;
        if (e < 64*64) {
            int i = e >> 6, j = e & 63;
            float dist = fabsf((float)(i - j));   // DELTA/TAU = 1
            tb[e] = logf(expf(-dist) + 1e-12f);
        } else if (e < 64*64 + 64*128) {
            int e2 = e - 64*64;
            int i = e2 >> 7, d = e2 & 127;
            int mm = d >> 1;
            float div = expf((float)(2*mm) * (-logf(10000.f)/128.f));
            float ang = (float)i * div;
            pe[e2] = (d & 1) ? cosf(ang) : sinf(ang);
        }
    }
}

// ---------------------------------------------------------------- FUSED: gather + te + MLP(h2) + MFMA Filt + softmax + ttcn
// 512 blocks (one per patch), 256 threads = 4 waves. Wave w handles cols [w*1024, w*1024+1024).
__global__ __launch_bounds__(256) void prep_ttcn_kernel(
    const float* __restrict__ data, const float* __restrict__ ts,
    const float* __restrict__ pmask, const int* __restrict__ pindex,
    const int* __restrict__ nbatch,
    const float* __restrict__ teW, const float* __restrict__ teB,
    const float* __restrict__ tePW, const float* __restrict__ tePB,
    const float* __restrict__ W1, const float* __restrict__ b1,
    const float* __restrict__ W2, const float* __restrict__ b2,
    const unsigned short* __restrict__ w3tb,  // [4096][128] bf16
    const float* __restrict__ b3,             // [4064]
    const float* __restrict__ tbias,          // [127]
    float* __restrict__ x)                    // [512][128]
{
    int n = blockIdx.x;
    int b = n >> 6, p = n & 63;
    __shared__ int s_start, s_len;
    __shared__ float mk[LL];
    __shared__ alignas(16) float Xs[LL*36];
    __shared__ alignas(16) float H1[LL*128];
    __shared__ alignas(16) unsigned short h2s[LL*136];
    int tid = threadIdx.x;
    if (tid == 0) {
        int start = 0;
        for (int j = 0; j < p; ++j) {
            float mv = pmask[b*PP + j];
            int pi = pindex[b*PP + j];
            start += (mv > 0.f) ? (pi > 0 ? pi : 0) : 0;
        }
        float mvp = pmask[b*PP + p];
        int pip = pindex[b*PP + p];
        s_len = (mvp > 0.f) ? (pip > 0 ? pip : 0) : 0;
        s_start = start;
    }
    __syncthreads();
    int start = s_start, len = s_len, nb2 = nbatch[b];
    if (tid < LL) {
        int l = tid;
        int idx = start + l;
        mk[l] = (l < len && idx < nb2) ? 1.f : 0.f;
    }
    __syncthreads();
    for (int e = tid; e < LL*PNT; e += 256) {
        int l = e >> 5, d = e & 31;
        float mv = mk[l];
        int idx = start + l;
        if (idx < 0) idx = 0;
        if (idx > LMAXX-1) idx = LMAXX-1;
        float val;
        if (d < INDIM) {
            val = (mv > 0.f) ? data[(b*LMAXX + idx)*INDIM + d] : 0.f;
        } else {
            float tsm = (mv > 0.f) ? ts[b*LMAXX + idx] : 0.f;
            if (d == INDIM) val = tsm * teW[0] + teB[0];
            else { int j = d - INDIM - 1; val = sinf(tsm * tePW[j] + tePB[j]); }
        }
        Xs[l*36 + d] = val;
    }
    __syncthreads();
    if (tid == 0) {
        float e = 0.f;
        for (int l = 0; l < LL; ++l) e += mk[l];
        x[n*HIDD + 127] = (e > 0.f) ? 1.f : 0.f;
    }
    // ---- MLP layer 1: all 256 threads (j = tid&127, l-half = tid>>7)
    {
        int j = tid & 127, lh = tid >> 7;   // rows lh*16 .. lh*16+15
        float acc[16];
        if (j < TTCNN) {
            #pragma unroll
            for (int il = 0; il < 16; ++il) acc[il] = b1[j];
            for (int d4 = 0; d4 < 8; ++d4) {
                float w0 = W1[(d4*4+0)*TTCNN + j];
                float w1 = W1[(d4*4+1)*TTCNN + j];
                float w2 = W1[(d4*4+2)*TTCNN + j];
                float w3 = W1[(d4*4+3)*TTCNN + j];
                #pragma unroll
                for (int il = 0; il < 16; ++il) {
                    float4 xv = *(float4*)&Xs[(lh*16 + il)*36 + d4*4];
                    acc[il] = fmaf(xv.x, w0, acc[il]);
                    acc[il] = fmaf(xv.y, w1, acc[il]);
                    acc[il] = fmaf(xv.z, w2, acc[il]);
                    acc[il] = fmaf(xv.w, w3, acc[il]);
                }
            }
            #pragma unroll
            for (int il = 0; il < 16; ++il) H1[(lh*16 + il)*128 + j] = fmaxf(acc[il], 0.f);
        } else {
            #pragma unroll
            for (int il = 0; il < 16; ++il) H1[(lh*16 + il)*128 + 127] = 0.f;
        }
    }
    __syncthreads();
    // ---- MLP layer 2 -> h2s (bf16)
    {
        int j = tid & 127, lh = tid >> 7;
        float acc[16];
        if (j < TTCNN) {
            #pragma unroll
            for (int il = 0; il < 16; ++il) acc[il] = b2[j];
            for (int k4 = 0; k4 < 32; ++k4) {
                int k = k4*4;
                float w0 = W2[(k+0)*TTCNN + j];
                float w1 = W2[(k+1)*TTCNN + j];
                float w2 = W2[(k+2)*TTCNN + j];
                float w3 = (k+3 < TTCNN) ? W2[(k+3)*TTCNN + j] : 0.f;
                #pragma unroll
                for (int il = 0; il < 16; ++il) {
                    float4 h = *(float4*)&H1[(lh*16 + il)*128 + k];
                    acc[il] = fmaf(h.x, w0, acc[il]);
                    acc[il] = fmaf(h.y, w1, acc[il]);
                    acc[il] = fmaf(h.z, w2, acc[il]);
                    acc[il] = fmaf(h.w, w3, acc[il]);
                }
            }
            #pragma unroll
            for (int il = 0; il < 16; ++il)
                h2s[(lh*16 + il)*136 + j] = f2bf(fmaxf(acc[il], 0.f));
        } else {
            #pragma unroll
            for (int il = 0; il < 16; ++il) h2s[(lh*16 + il)*136 + 127] = 0;
        }
    }
    __syncthreads();
    // ---- MFMA phase: wave handles 32 t-values (1024 cols)
    int wave = tid >> 6, lane = tid & 63;
    int li = lane & 15, hi = lane >> 4;
    short8v a[2][4];
    #pragma unroll
    for (int mt = 0; mt < 2; ++mt)
        #pragma unroll
        for (int kk = 0; kk < 4; ++kk)
            a[mt][kk] = *(short8v*)&h2s[(mt*16 + li)*136 + kk*32 + hi*8];
    float mkr[8], off8[8], xv0[8], xv1[8];
    #pragma unroll
    for (int mt = 0; mt < 2; ++mt)
        #pragma unroll
        for (int r4 = 0; r4 < 4; ++r4) {
            int i = mt*4 + r4;
            int rr = mt*16 + hi*4 + r4;
            float mv = mk[rr];
            mkr[i] = mv;
            off8[i] = (1.f - mv) * (-30.f);   // valid: 0 ; masked: -30
            xv0[i] = Xs[rr*36 + li];
            xv1[i] = Xs[rr*36 + 16 + li];
        }
    int cwbase = wave*1024;
    for (int tl = 0; tl < 32; ++tl) {
        int c0 = cwbase + tl*32;
        float4v acc[2][2] = {};
        #pragma unroll
        for (int nt2 = 0; nt2 < 2; ++nt2) {
            const unsigned short* bp = &w3tb[(size_t)(c0 + nt2*16 + li)*128 + hi*8];
            #pragma unroll
            for (int kk = 0; kk < 4; ++kk) {
                short8v bf = *(const short8v*)&bp[kk*32];
                acc[0][nt2] = __builtin_amdgcn_mfma_f32_16x16x32_bf16(a[0][kk], bf, acc[0][nt2], 0, 0, 0);
                acc[1][nt2] = __builtin_amdgcn_mfma_f32_16x16x32_bf16(a[1][kk], bf, acc[1][nt2], 0, 0, 0);
            }
        }
        int t = c0 >> 5;
        float colv2 = 0.f;
        #pragma unroll
        for (int nt2 = 0; nt2 < 2; ++nt2) {
            int cglob = c0 + nt2*16 + li;
            float bv = (cglob < 4064) ? b3[cglob] : 0.f;
            float s = 0.f, w = 0.f;
            #pragma unroll
            for (int mt = 0; mt < 2; ++mt)
                #pragma unroll
                for (int r4 = 0; r4 < 4; ++r4) {
                    int i = mt*4 + r4;
                    float fm = (acc[mt][nt2][r4] + bv)*mkr[i] + off8[i];
                    float e = __expf(fm);
                    s += e;
                    w = fmaf(e, (nt2 == 0) ? xv0[i] : xv1[i], w);
                }
            s += __shfl_xor(s, 16); w += __shfl_xor(w, 16);
            s += __shfl_xor(s, 32); w += __shfl_xor(w, 32);
            colv2 = fmaf(w, __builtin_amdgcn_rcpf(s), colv2);
        }
        colv2 += __shfl_xor(colv2, 1);
        colv2 += __shfl_xor(colv2, 2);
        colv2 += __shfl_xor(colv2, 4);
        colv2 += __shfl_xor(colv2, 8);
        if (lane == 0 && t < TTCNN)
            x[n*HIDD + t] = fmaxf(colv2 + tbias[t], 0.f);
    }
}

// ---------------------------------------------------------------- generic fused linear (R6 version)
__global__ __launch_bounds__(256) void lin_kernel(
    const float* __restrict__ A, int lda,
    const float* __restrict__ W0, const float* __restrict__ Wb0,
    const float* __restrict__ W1, const float* __restrict__ Wb1,
    const float* __restrict__ W2, const float* __restrict__ Wb2,
    float* __restrict__ O0, float* __restrict__ O1, float* __restrict__ O2,
    int M, int K, int N, int epi,
    const float* __restrict__ xres, const float* __restrict__ xlast_in,
    float* __restrict__ xlast_out,
    const float* __restrict__ pmk, const float* __restrict__ pe,
    const float* __restrict__ g, const float* __restrict__ bt)
{
    __shared__ alignas(16) float As[8*68];
    __shared__ float red[4][4][2];
    int tid = threadIdx.x;
    int cloc = tid & 127, rh = tid >> 7;
    int c = blockIdx.z*128 + cloc;
    int r0 = blockIdx.x*8;
    const float* W; const float* Wb; float* O;
    if (blockIdx.y == 0)      { W = W0; Wb = Wb0; O = O0; }
    else if (blockIdx.y == 1) { W = W1; Wb = Wb1; O = O1; }
    else                      { W = W2; Wb = Wb2; O = O2; }
    float acc0 = 0.f, acc1 = 0.f, acc2 = 0.f, acc3 = 0.f;
    for (int kc = 0; kc < K; kc += 64) {
        __syncthreads();
        if (tid < 128) {
            int row = tid >> 4, kk = (tid & 15)*4;
            int r = r0 + row;
            float4 v = make_float4(0.f, 0.f, 0.f, 0.f);
            if (r < M) v = *(const float4*)&A[(size_t)r*lda + kc + kk];
            *(float4*)&As[row*68 + kk] = v;
        }
        __syncthreads();
        const float* wp = &W[(size_t)kc*N + c];
        #pragma unroll 4
        for (int kk4 = 0; kk4 < 16; ++kk4) {
            float w0 = wp[(size_t)(kk4*4+0)*N];
            float w1 = wp[(size_t)(kk4*4+1)*N];
            float w2 = wp[(size_t)(kk4*4+2)*N];
            float w3 = wp[(size_t)(kk4*4+3)*N];
            float4 a0 = *(float4*)&As[(rh*4+0)*68 + kk4*4];
            float4 a1 = *(float4*)&As[(rh*4+1)*68 + kk4*4];
            float4 a2 = *(float4*)&As[(rh*4+2)*68 + kk4*4];
            float4 a3 = *(float4*)&As[(rh*4+3)*68 + kk4*4];
            acc0 += a0.x*w0 + a0.y*w1 + a0.z*w2 + a0.w*w3;
            acc1 += a1.x*w0 + a1.y*w1 + a1.z*w2 + a1.w*w3;
            acc2 += a2.x*w0 + a2.y*w1 + a2.z*w2 + a2.w*w3;
            acc3 += a3.x*w0 + a3.y*w1 + a3.z*w2 + a3.w*w3;
        }
    }
    float bv = Wb ? Wb[c] : 0.f;
    float val[4] = {acc0 + bv, acc1 + bv, acc2 + bv, acc3 + bv};
    int rbase = r0 + rh*4;
    if (epi == EPI_NONE || epi == EPI_RELU) {
        #pragma unroll
        for (int i = 0; i < 4; ++i) {
            int r = rbase + i;
            if (r < M) {
                float v = val[i];
                if (epi == EPI_RELU) v = fmaxf(v, 0.f);
                O[(size_t)r*N + c] = v;
            }
        }
    } else if (epi == EPI_GA) {
        #pragma unroll
        for (int i = 0; i < 4; ++i) {
            int r = rbase + i;
            float xr = xres[r*128 + cloc];
            float pmv = pmk[r];
            float pev = pe[(r & 63)*128 + cloc];
            xlast_out[r*128 + cloc] = xr;
            O[r*128 + cloc] = xr + val[i]*pmv + pev;
        }
    } else {
        float tv[4], s[4], s2[4];
        #pragma unroll
        for (int i = 0; i < 4; ++i) {
            int r = rbase + i;
            tv[i] = xres[r*128 + cloc] + val[i];
            s[i] = tv[i];
            s2[i] = tv[i]*tv[i];
        }
        #pragma unroll
        for (int i = 0; i < 4; ++i) {
            for (int off = 32; off >= 1; off >>= 1) {
                s[i]  += __shfl_xor(s[i],  off);
                s2[i] += __shfl_xor(s2[i], off);
            }
        }
        int wid = tid >> 6;
        if ((tid & 63) == 0) {
            #pragma unroll
            for (int i = 0; i < 4; ++i) { red[wid][i][0] = s[i]; red[wid][i][1] = s2[i]; }
        }
        __syncthreads();
        int pw = wid ^ 1;
        #pragma unroll
        for (int i = 0; i < 4; ++i) {
            float st  = red[wid][i][0] + red[pw][i][0];
            float s2t = red[wid][i][1] + red[pw][i][1];
            float mean = st * (1.f/128.f);
            float var = s2t * (1.f/128.f) - mean*mean;
            float rs = rsqrtf(var + 1e-5f);
            float y = (tv[i] - mean)*rs*g[cloc] + bt[cloc];
            int r = rbase + i;
            if (epi == EPI_LN) O[r*128 + cloc] = y;
            else               O[r*128 + cloc] = (xlast_in[r*128 + cloc] + y)*pmk[r];
        }
    }
}

// ---------------------------------------------------------------- FF2 split-K partials (K=2048 -> 8 x 256)
__global__ __launch_bounds__(256) void ff2_partial_kernel(
    const float* __restrict__ A,   // [512][2048]
    const float* __restrict__ W,   // [2048][128]
    float* __restrict__ PART)      // [8][512][128]
{
    __shared__ alignas(16) float As[8*68];
    int tid = threadIdx.x;
    int cloc = tid & 127, rh = tid >> 7;
    int r0 = blockIdx.x*8;
    int kz = blockIdx.z*256;
    float acc0 = 0.f, acc1 = 0.f, acc2 = 0.f, acc3 = 0.f;
    for (int kc = kz; kc < kz + 256; kc += 64) {
        __syncthreads();
        if (tid < 128) {
            int row = tid >> 4, kk = (tid & 15)*4;
            *(float4*)&As[row*68 + kk] = *(const float4*)&A[(size_t)(r0+row)*2048 + kc + kk];
        }
        __syncthreads();
        const float* wp = &W[(size_t)kc*128 + cloc];
        #pragma unroll 4
        for (int kk4 = 0; kk4 < 16; ++kk4) {
            float w0 = wp[(size_t)(kk4*4+0)*128];
            float w1 = wp[(size_t)(kk4*4+1)*128];
            float w2 = wp[(size_t)(kk4*4+2)*128];
            float w3 = wp[(size_t)(kk4*4+3)*128];
            float4 a0 = *(float4*)&As[(rh*4+0)*68 + kk4*4];
            float4 a1 = *(float4*)&As[(rh*4+1)*68 + kk4*4];
            float4 a2 = *(float4*)&As[(rh*4+2)*68 + kk4*4];
            float4 a3 = *(float4*)&As[(rh*4+3)*68 + kk4*4];
            acc0 += a0.x*w0 + a0.y*w1 + a0.z*w2 + a0.w*w3;
            acc1 += a1.x*w0 + a1.y*w1 + a1.z*w2 + a1.w*w3;
            acc2 += a2.x*w0 + a2.y*w1 + a2.z*w2 + a2.w*w3;
            acc3 += a3.x*w0 + a3.y*w1 + a3.z*w2 + a3.w*w3;
        }
    }
    float* pb = &PART[((size_t)blockIdx.z*512 + r0 + rh*4)*128 + cloc];
    pb[0]     = acc0;
    pb[128]   = acc1;
    pb[256]   = acc2;
    pb[384]   = acc3;
}

// ---------------------------------------------------------------- FF2 epilogue: sum partials + bias + LN2 + final residual
__global__ void ln2f_kernel(const float* __restrict__ PART, const float* __restrict__ b2,
                            const float* __restrict__ xres, const float* __restrict__ xlast,
                            const float* __restrict__ pmk,
                            const float* __restrict__ g, const float* __restrict__ bt,
                            float* __restrict__ xout)
{
    int r = blockIdx.x, c = threadIdx.x;  // 512 blocks x 128 threads
    float v = b2[c];
    #pragma unroll
    for (int z = 0; z < 8; ++z) v += PART[((size_t)z*512 + r)*128 + c];
    float tv = xres[r*128 + c] + v;
    float s = tv, s2 = tv*tv;
    for (int off = 32; off >= 1; off >>= 1) {
        s  += __shfl_xor(s,  off);
        s2 += __shfl_xor(s2, off);
    }
    __shared__ float red[2][2];
    int w = c >> 6;
    if ((c & 63) == 0) { red[w][0] = s; red[w][1] = s2; }
    __syncthreads();
    float st  = red[0][0] + red[1][0];
    float s2t = red[0][1] + red[1][1];
    float mean = st * (1.f/128.f);
    float var = s2t * (1.f/128.f) - mean*mean;
    float y = (tv - mean)*rsqrtf(var + 1e-5f)*g[c] + bt[c];
    xout[r*128 + c] = (xlast[r*128 + c] + y)*pmk[r];
}

// ---------------------------------------------------------------- 64-token MHA (4 heads, dh=32), split q-rows x2
__global__ __launch_bounds__(256) void attn_kernel(
    const float* __restrict__ q, const float* __restrict__ k, const float* __restrict__ v,
    float* __restrict__ out, const float* __restrict__ tb,
    const float* __restrict__ pmk, int flags)
{
    int bid = blockIdx.x;                       // 64 = 8b x 4h x 2half
    int b = bid >> 3, h = (bid >> 1) & 3, half = bid & 1;
    int rbase = half*32;
    __shared__ alignas(16) float qs[32*36];
    __shared__ alignas(16) float ks[64*36];
    __shared__ alignas(16) float vs[64*36];
    __shared__ float as_[32*68];
    int tid = threadIdx.x;
    {
        int m = tid >> 3, d4 = (tid & 7)*4;
        *(float4*)&qs[m*36 + d4] = *(const float4*)&q[(b*64 + rbase + m)*128 + h*32 + d4];
    }
    for (int f = tid; f < 512; f += 256) {
        int m = f >> 3, d4 = (f & 7)*4;
        int gofs = (b*64 + m)*128 + h*32 + d4;
        *(float4*)&ks[m*36 + d4] = *(const float4*)&k[gofs];
        *(float4*)&vs[m*36 + d4] = *(const float4*)&v[gofs];
    }
    __syncthreads();
    int r = tid >> 3, qd = tid & 7;
    float sreg[8];
    #pragma unroll
    for (int j = 0; j < 8; ++j) {
        int cc = j*8 + qd;
        float acc = 0.f;
        #pragma unroll
        for (int d4 = 0; d4 < 8; ++d4) {
            float4 a = *(float4*)&qs[r*36 + d4*4];
            float4 bb = *(float4*)&ks[cc*36 + d4*4];
            acc += a.x*bb.x + a.y*bb.y + a.z*bb.z + a.w*bb.w;
        }
        float s = acc * 0.17677669529663687f;
        if (flags & 1) s += tb[(rbase + r)*64 + cc];
        if (flags & 2) { if (pmk[b*64 + cc] <= 0.f) s = -1e9f; }
        sreg[j] = s;
    }
    float m = sreg[0];
    #pragma unroll
    for (int j = 1; j < 8; ++j) m = fmaxf(m, sreg[j]);
    m = fmaxf(m, __shfl_xor(m, 1));
    m = fmaxf(m, __shfl_xor(m, 2));
    m = fmaxf(m, __shfl_xor(m, 4));
    float ssum = 0.f;
    #pragma unroll
    for (int j = 0; j < 8; ++j) { sreg[j] = __expf(sreg[j] - m); ssum += sreg[j]; }
    ssum += __shfl_xor(ssum, 1);
    ssum += __shfl_xor(ssum, 2);
    ssum += __shfl_xor(ssum, 4);
    float inv = __builtin_amdgcn_rcpf(ssum);
    #pragma unroll
    for (int j = 0; j < 8; ++j) as_[r*68 + j*8 + qd] = sreg[j]*inv;
    __syncthreads();
    float o0 = 0.f, o1 = 0.f, o2 = 0.f, o3 = 0.f;
    int d0 = qd*4;
    for (int cc = 0; cc < 64; ++cc) {
        float a = as_[r*68 + cc];
        float4 v4 = *(float4*)&vs[cc*36 + d0];
        o0 += a*v4.x; o1 += a*v4.y; o2 += a*v4.z; o3 += a*v4.w;
    }
    *(float4*)&out[(b*64 + rbase + r)*128 + h*32 + d0] = make_float4(o0, o1, o2, o3);
}

// ---------------------------------------------------------------- cls: q-proj + attention + Weff logits (fused)
__global__ __launch_bounds__(256) void cls_attn_kernel(
    const float* __restrict__ clsq, const float* __restrict__ Wq, const float* __restrict__ bq,
    const float* __restrict__ k, const float* __restrict__ v,
    const float* __restrict__ pmk,
    const float* __restrict__ Wo, const float* __restrict__ bo,
    const float* __restrict__ WoutW, const float* __restrict__ boutB,
    float* __restrict__ outp)
{
    int b = blockIdx.x;
    __shared__ alignas(16) float ks[64*132];
    __shared__ alignas(16) float vs[64*132];
    __shared__ alignas(16) float q5[5*132];
    __shared__ float cq[5*128];
    __shared__ float sb[5*68];
    __shared__ float z[5*132];
    __shared__ float wef[129];
    int tid = threadIdx.x;
    for (int f = tid; f < 64*32; f += 256) {
        int m = f >> 5, d4 = (f & 31)*4;
        *(float4*)&ks[m*132 + d4] = *(const float4*)&k[(b*64+m)*128 + d4];
        *(float4*)&vs[m*132 + d4] = *(const float4*)&v[(b*64+m)*128 + d4];
    }
    for (int e = tid; e < 5*128; e += 256) {
        cq[e] = clsq[e];
        z[(e >> 7)*132 + (e & 127)] = 0.f;
    }
    __syncthreads();
    for (int it = tid; it < 5*128; it += 256) {
        int qr = it >> 7, d = it & 127;
        float a = bq[d];
        for (int kk = 0; kk < 128; ++kk) a += cq[qr*128 + kk]*Wq[kk*128 + d];
        q5[qr*132 + d] = a;
    }
    if (tid < 128) {
        float s = 0.f;
        for (int cc = 0; cc < 128; ++cc) s += Wo[tid*128 + cc]*WoutW[cc];
        wef[tid] = s;
    } else if (tid == 128) {
        float t = boutB[0];
        for (int cc = 0; cc < 128; ++cc) t += bo[cc]*WoutW[cc];
        wef[128] = t;
    }
    __syncthreads();
    for (int h = 0; h < 4; ++h) {
        for (int it = tid; it < 5*64; it += 256) {
            int qr = it >> 6, cc = it & 63;
            float acc = 0.f;
            #pragma unroll
            for (int d4 = 0; d4 < 8; ++d4) {
                float4 a = *(float4*)&q5[qr*132 + h*32 + d4*4];
                float4 bb = *(float4*)&ks[cc*132 + h*32 + d4*4];
                acc += a.x*bb.x + a.y*bb.y + a.z*bb.z + a.w*bb.w;
            }
            float s = acc * 0.17677669529663687f;
            if (pmk[b*64 + cc] <= 0.f) s = -1e9f;
            sb[qr*68 + cc] = s;
        }
        __syncthreads();
        if (tid < 5) {
            float m = -3e38f;
            for (int cc = 0; cc < 64; ++cc) m = fmaxf(m, sb[tid*68 + cc]);
            float ssum = 0.f;
            for (int cc = 0; cc < 64; ++cc) {
                float e = __expf(sb[tid*68 + cc] - m);
                sb[tid*68 + cc] = e;
                ssum += e;
            }
            float inv = __builtin_amdgcn_rcpf(ssum);
            for (int cc = 0; cc < 64; ++cc) sb[tid*68 + cc] *= inv;
        }
        __syncthreads();
        for (int it = tid; it < 5*32; it += 256) {
            int qr = it >> 5, d = it & 31;
            float acc = 0.f;
            for (int cc = 0; cc < 64; ++cc) acc += sb[qr*68 + cc]*vs[cc*132 + h*32 + d];
            z[qr*132 + h*32 + d] = acc;
        }
        __syncthreads();
    }
    if (tid < 5) {
        float acc = wef[128];
        for (int d = 0; d < 128; ++d) acc += z[tid*132 + d]*wef[d];
        outp[b*5 + tid] = acc;
    }
}

// ================================================================ launch
extern "C" void kernel_launch(void* const* d_in, const int* in_sizes, int n_in,
                              void* d_out, int out_size, void* d_ws, size_t ws_size,
                              hipStream_t stream)
{
    (void)n_in; (void)out_size; (void)ws_size;
    #define FP(i) ((const float*)d_in[i])
    const float* data = FP(0);
    const float* ts   = FP(1);
    const float* pmask= FP(2);
    const int*   pidx = (const int*)d_in[3];
    const int*   nb   = (const int*)d_in[4];
    const float* teW  = FP(5);
    const float* teB  = FP(6);
    const float* tePW = FP(7);
    const float* tePB = FP(8);
    const float* fgW1 = FP(9);
    const float* fgb1 = FP(10);
    const float* fgW2 = FP(11);
    const float* fgb2 = FP(12);
    const float* fgW3 = FP(13);
    const float* fgb3 = FP(14);
    const float* Tb   = FP(15);
    const float *gaWq,*gaWk,*gaWv,*gaWo,*tfWq,*tfWk,*tfWv,*tfWo;
    const float *gabq,*gabk,*gabv,*gabo,*tfbq,*tfbk,*tfbv,*tfbo,*ffb2;
    const float *ln1g,*ln1b,*ln2g,*ln2b,*ffW1,*ffb1,*ffW2;
    const float *clsq,*clsWq,*clsWk,*clsWv,*clsWo,*clsbq,*clsbk,*clsbv,*clsbo,*cloW,*clob;
    if (in_sizes[17] == 2*128*128) {  // setup_inputs dict order
        gaWq=FP(16); gaWk=FP(17); gaWv=FP(18); gaWo=FP(19);
        tfWq=FP(20); tfWk=FP(21); tfWv=FP(22); tfWo=FP(23);
        gabq=FP(24); gabk=FP(25); gabv=FP(26); gabo=FP(27);
        tfbq=FP(28); tfbk=FP(29); tfbv=FP(30); tfbo=FP(31);
        ffb2=FP(32); ln1g=FP(33); ln1b=FP(34); ln2g=FP(35); ln2b=FP(36);
        ffW1=FP(37); ffb1=FP(38); ffW2=FP(39);
        clsq=FP(40); clsWq=FP(41); clsWk=FP(42); clsWv=FP(43); clsWo=FP(44);
        clsbq=FP(45); clsbk=FP(46); clsbv=FP(47); clsbo=FP(48); cloW=FP(49); clob=FP(50);
    } else {                          // reference() signature order
        gaWq=FP(16); gabq=FP(17); gaWk=FP(18); gabk=FP(19);
        gaWv=FP(20); gabv=FP(21); gaWo=FP(22); gabo=FP(23);
        tfWq=FP(24); tfbq=FP(25); tfWk=FP(26); tfbk=FP(27);
        tfWv=FP(28); tfbv=FP(29); tfWo=FP(30); tfbo=FP(31);
        ln1g=FP(32); ln1b=FP(33); ffW1=FP(34); ffb1=FP(35); ffW2=FP(36); ffb2=FP(37);
        ln2g=FP(38); ln2b=FP(39);
        clsq=FP(40); clsWq=FP(41); clsbq=FP(42); clsWk=FP(43); clsbk=FP(44);
        clsWv=FP(45); clsbv=FP(46); clsWo=FP(47); clsbo=FP(48); cloW=FP(49); clob=FP(50);
    }

    float* ws   = (float*)d_ws;
    unsigned short* W3TB = (unsigned short*)ws;   // 4096*128 bf16 = 262144 floats
    float* X    = ws + 262144;
    float* XLAST= X + 65536;
    float* Q    = XLAST + 65536;
    float* Kb   = Q + 65536;
    float* Vb   = Kb + 65536;
    float* ATT  = Vb + 65536;
    float* HIDB = ATT + 65536;            // 1048576
    float* PART = HIDB + 1048576;         // 524288
    float* TBT  = PART + 524288;          // 4096
    float* PET  = TBT + 4096;             // 8192

    tables_w3t_kernel<<<2096, 256, 0, stream>>>(fgW3, W3TB, TBT, PET);
    prep_ttcn_kernel<<<512, 256, 0, stream>>>(data, ts, pmask, pidx, nb, teW, teB, tePW, tePB,
                                              fgW1, fgb1, fgW2, fgb2, W3TB, fgb3, Tb, X);

    for (int l = 0; l < 2; ++l) {
        const float* Wq = gaWq + l*16384; const float* bq = gabq + l*128;
        const float* Wk = gaWk + l*16384; const float* bk = gabk + l*128;
        const float* Wv = gaWv + l*16384; const float* bv = gabv + l*128;
        const float* Wo = gaWo + l*16384; const float* bo = gabo + l*128;
        // ga qkv
        lin_kernel<<<dim3(64,3,1), 256, 0, stream>>>(X, 128, Wq,bq, Wk,bk, Wv,bv, Q,Kb,Vb,
            512,128,128, EPI_NONE, nullptr,nullptr,nullptr,nullptr,nullptr,nullptr,nullptr);
        attn_kernel<<<64, 256, 0, stream>>>(Q, Kb, Vb, ATT, TBT, pmask, 3);
        // ga out-proj: x = x + ga*pm + pe ; save x_last
        lin_kernel<<<dim3(64,1,1), 256, 0, stream>>>(ATT, 128, Wo,bo, Wo,bo, Wo,bo, X,X,X,
            512,128,128, EPI_GA, X, nullptr, XLAST, pmask, PET, nullptr, nullptr);
        // tf qkv
        const float* Wq2 = tfWq + l*16384; const float* bq2 = tfbq + l*128;
        const float* Wk2 = tfWk + l*16384; const float* bk2 = tfbk + l*128;
        const float* Wv2 = tfWv + l*16384; const float* bv2 = tfbv + l*128;
        const float* Wo2 = tfWo + l*16384; const float* bo2 = tfbo + l*128;
        lin_kernel<<<dim3(64,3,1), 256, 0, stream>>>(X, 128, Wq2,bq2, Wk2,bk2, Wv2,bv2, Q,Kb,Vb,
            512,128,128, EPI_NONE, nullptr,nullptr,nullptr,nullptr,nullptr,nullptr,nullptr);
        attn_kernel<<<64, 256, 0, stream>>>(Q, Kb, Vb, ATT, TBT, pmask, 0);
        // tf out-proj + LN1(x + a)
        lin_kernel<<<dim3(64,1,1), 256, 0, stream>>>(ATT, 128, Wo2,bo2, Wo2,bo2, Wo2,bo2, X,X,X,
            512,128,128, EPI_LN, X, nullptr, nullptr, nullptr, nullptr, ln1g + l*128, ln1b + l*128);
        // FF1 relu
        lin_kernel<<<dim3(64,1,16), 256, 0, stream>>>(X, 128,
            ffW1 + (size_t)l*128*2048, ffb1 + l*2048, ffW1, ffb1, ffW1, ffb1, HIDB,HIDB,HIDB,
            512,128,2048, EPI_RELU, nullptr,nullptr,nullptr,nullptr,nullptr,nullptr,nullptr);
        // FF2 split-K partials + LN2 epilogue
        ff2_partial_kernel<<<dim3(64,1,8), 256, 0, stream>>>(HIDB, ffW2 + (size_t)l*2048*128, PART);
        ln2f_kernel<<<512, 128, 0, stream>>>(PART, ffb2 + l*128, X, XLAST, pmask,
                                             ln2g + l*128, ln2b + l*128, X);
    }

    // cls head: K/V projection then fused q-proj + attention + logits
    lin_kernel<<<dim3(64,2,1), 256, 0, stream>>>(X, 128, clsWk,clsbk, clsWv,clsbv, clsWv,clsbv,
        Kb,Vb,Vb, 512,128,128, EPI_NONE, nullptr,nullptr,nullptr,nullptr,nullptr,nullptr,nullptr);
    cls_attn_kernel<<<8, 256, 0, stream>>>(clsq, clsWq, clsbq, Kb, Vb, pmask,
                                           clsWo, clsbo, cloW, clob, (float*)d_out);
}